// Round 14
// baseline (350.741 us; speedup 1.0000x reference)
//
#include <hip/hip_runtime.h>
#include <hip/hip_bf16.h>
#include <math.h>

#define EPS 1e-5f

typedef __attribute__((ext_vector_type(8))) short bf16x8;
typedef __attribute__((ext_vector_type(4))) float f32x4;

__device__ __forceinline__ unsigned short f2bf(float f) {
    unsigned u = __float_as_uint(f);
    unsigned r = (u + 0x7FFFu + ((u >> 16) & 1u)) >> 16;   // RNE
    return (unsigned short)r;
}
__device__ __forceinline__ unsigned f2bf2(float lo, float hi) {
    return (unsigned)f2bf(lo) | ((unsigned)f2bf(hi) << 16);
}
__device__ __forceinline__ float bf2f(unsigned short u) {
    return __uint_as_float((unsigned)u << 16);
}
__device__ __forceinline__ void bfu2(unsigned u, float& lo, float& hi) {
    lo = __uint_as_float(u << 16);
    hi = __uint_as_float(u & 0xFFFF0000u);
}

// ---------- weight pack: 9 matrices fp32 [128k x 128n] -> bf16 B-fragment order ----------
// fragment (nt,col0) = W column col0*8+nt -> lane's 8 accs are 8 consecutive channels.
__global__ __launch_bounds__(256) void pack_w9(const float* __restrict__ W0, const float* __restrict__ W1,
                                               const float* __restrict__ W2, const float* __restrict__ W3,
                                               const float* __restrict__ W4, const float* __restrict__ W5,
                                               const float* __restrict__ W6, const float* __restrict__ W7,
                                               const float* __restrict__ W8, unsigned short* __restrict__ out) {
    int t = blockIdx.x * 256 + threadIdx.x;
    if (t >= 9 * 16384) return;
    int mat = t >> 14, r = t & 16383;
    const float* W;
    switch (mat) {
        case 0: W = W0; break; case 1: W = W1; break; case 2: W = W2; break;
        case 3: W = W3; break; case 4: W = W4; break; case 5: W = W5; break;
        case 6: W = W6; break; case 7: W = W7; break; default: W = W8; break;
    }
    int j = r & 7, lane = (r >> 3) & 63, nt = (r >> 9) & 7, kc = r >> 12;
    int k = kc * 32 + (lane >> 4) * 8 + j;
    int n = (lane & 15) * 8 + nt;
    out[t] = f2bf(W[k * 128 + n]);
}

// ---------- fp32 -> bf16 elementwise ----------
__global__ __launch_bounds__(256) void f32_to_bf16(const float* __restrict__ in,
                                                   unsigned short* __restrict__ out, int n4) {
    int i = blockIdx.x * 256 + threadIdx.x;
    if (i >= n4) return;
    float4 v = ((const float4*)in)[i];
    ushort4 o = make_ushort4(f2bf(v.x), f2bf(v.y), f2bf(v.z), f2bf(v.w));
    ((ushort4*)out)[i] = o;
}

// ---------- MFMA GEMM (single matrix, coalesced epilogue) ----------
template <int ACT, int WBF>
__global__ __launch_bounds__(256) void gemm_mfma(const unsigned short* __restrict__ Abf,
                                                 const unsigned short* __restrict__ Bp,
                                                 const float* __restrict__ bias,
                                                 float* __restrict__ C,
                                                 unsigned short* __restrict__ Cbf, int M) {
    int wave = threadIdx.x >> 6, lane = threadIdx.x & 63;
    int base = blockIdx.x * 64 + wave * 16;
    int m = lane & 15, kg = lane >> 4;
    int arow = base + m; if (arow >= M) arow = M - 1;
    const unsigned short* Aptr = Abf + (size_t)arow * 128 + kg * 8;
    f32x4 acc[8];
#pragma unroll
    for (int nt = 0; nt < 8; ++nt) acc[nt] = (f32x4)(0.f);
#pragma unroll
    for (int kc = 0; kc < 4; ++kc) {
        bf16x8 a = *(const bf16x8*)(Aptr + kc * 32);
        const unsigned short* bp = Bp + (size_t)kc * 4096 + (size_t)lane * 8;
#pragma unroll
        for (int nt = 0; nt < 8; ++nt) {
            bf16x8 b = *(const bf16x8*)(bp + nt * 512);
            acc[nt] = __builtin_amdgcn_mfma_f32_16x16x32_bf16(a, b, acc[nt], 0, 0, 0);
        }
    }
    int col0 = lane & 15;
    int r0 = base + (lane >> 4) * 4;
    float4 bl = *(const float4*)&bias[col0 * 8];
    float4 bh = *(const float4*)&bias[col0 * 8 + 4];
#pragma unroll
    for (int r = 0; r < 4; ++r) {
        int ro = r0 + r;
        if (ro < M) {
            float v0 = acc[0][r] + bl.x, v1 = acc[1][r] + bl.y;
            float v2 = acc[2][r] + bl.z, v3 = acc[3][r] + bl.w;
            float v4 = acc[4][r] + bh.x, v5 = acc[5][r] + bh.y;
            float v6 = acc[6][r] + bh.z, v7 = acc[7][r] + bh.w;
            if (ACT) {
                v0 = fmaxf(v0, 0.f); v1 = fmaxf(v1, 0.f); v2 = fmaxf(v2, 0.f); v3 = fmaxf(v3, 0.f);
                v4 = fmaxf(v4, 0.f); v5 = fmaxf(v5, 0.f); v6 = fmaxf(v6, 0.f); v7 = fmaxf(v7, 0.f);
            }
            size_t o = (size_t)ro * 128 + col0 * 8;
            *(float4*)&C[o]     = make_float4(v0, v1, v2, v3);
            *(float4*)&C[o + 4] = make_float4(v4, v5, v6, v7);
            if (WBF)
                *(uint4*)&Cbf[o] = make_uint4(f2bf2(v0, v1), f2bf2(v2, v3),
                                              f2bf2(v4, v5), f2bf2(v6, v7));
        }
    }
}

// ---------- 2-matrix fused GEMM: q -> qbf, k -> kvbf[0..128) (both bf16) ----------
__global__ __launch_bounds__(256) void gemm_qk(const unsigned short* __restrict__ Abf,
                                               const unsigned short* __restrict__ Bq,
                                               const unsigned short* __restrict__ Bk,
                                               const float* __restrict__ bq,
                                               const float* __restrict__ bk,
                                               unsigned short* __restrict__ qbf,
                                               unsigned short* __restrict__ kvbf, int M) {
    int wave = threadIdx.x >> 6, lane = threadIdx.x & 63;
    int base = blockIdx.x * 64 + wave * 16;
    int m = lane & 15, kg = lane >> 4;
    int arow = base + m; if (arow >= M) arow = M - 1;
    const unsigned short* Aptr = Abf + (size_t)arow * 128 + kg * 8;
    f32x4 aq[8], ak[8];
#pragma unroll
    for (int nt = 0; nt < 8; ++nt) { aq[nt] = (f32x4)(0.f); ak[nt] = (f32x4)(0.f); }
#pragma unroll
    for (int kc = 0; kc < 4; ++kc) {
        bf16x8 a = *(const bf16x8*)(Aptr + kc * 32);
        size_t boff = (size_t)kc * 4096 + (size_t)lane * 8;
#pragma unroll
        for (int nt = 0; nt < 8; ++nt) {
            bf16x8 b0 = *(const bf16x8*)(Bq + boff + nt * 512);
            aq[nt] = __builtin_amdgcn_mfma_f32_16x16x32_bf16(a, b0, aq[nt], 0, 0, 0);
            bf16x8 b1 = *(const bf16x8*)(Bk + boff + nt * 512);
            ak[nt] = __builtin_amdgcn_mfma_f32_16x16x32_bf16(a, b1, ak[nt], 0, 0, 0);
        }
    }
    int col0 = lane & 15;
    int r0 = base + (lane >> 4) * 4;
    float4 bql = *(const float4*)&bq[col0 * 8], bqh = *(const float4*)&bq[col0 * 8 + 4];
    float4 bkl = *(const float4*)&bk[col0 * 8], bkh = *(const float4*)&bk[col0 * 8 + 4];
#pragma unroll
    for (int r = 0; r < 4; ++r) {
        int ro = r0 + r;
        if (ro < M) {
            size_t qo = (size_t)ro * 128 + col0 * 8;
            size_t kvo = (size_t)ro * 256 + col0 * 8;
            *(uint4*)&qbf[qo] = make_uint4(
                f2bf2(aq[0][r] + bql.x, aq[1][r] + bql.y), f2bf2(aq[2][r] + bql.z, aq[3][r] + bql.w),
                f2bf2(aq[4][r] + bqh.x, aq[5][r] + bqh.y), f2bf2(aq[6][r] + bqh.z, aq[7][r] + bqh.w));
            *(uint4*)&kvbf[kvo] = make_uint4(
                f2bf2(ak[0][r] + bkl.x, ak[1][r] + bkl.y), f2bf2(ak[2][r] + bkl.z, ak[3][r] + bkl.w),
                f2bf2(ak[4][r] + bkh.x, ak[5][r] + bkh.y), f2bf2(ak[6][r] + bkh.z, ak[7][r] + bkh.w));
        }
    }
}

// ---------- 2-matrix fused GEMM: v -> kvbf[128..256) (bf16), skip -> xr (fp32) ----------
__global__ __launch_bounds__(256) void gemm_vs(const unsigned short* __restrict__ Abf,
                                               const unsigned short* __restrict__ Bv,
                                               const unsigned short* __restrict__ Bs,
                                               const float* __restrict__ bv,
                                               const float* __restrict__ bs,
                                               unsigned short* __restrict__ kvbf,
                                               float* __restrict__ xr, int M) {
    int wave = threadIdx.x >> 6, lane = threadIdx.x & 63;
    int base = blockIdx.x * 64 + wave * 16;
    int m = lane & 15, kg = lane >> 4;
    int arow = base + m; if (arow >= M) arow = M - 1;
    const unsigned short* Aptr = Abf + (size_t)arow * 128 + kg * 8;
    f32x4 av[8], as_[8];
#pragma unroll
    for (int nt = 0; nt < 8; ++nt) { av[nt] = (f32x4)(0.f); as_[nt] = (f32x4)(0.f); }
#pragma unroll
    for (int kc = 0; kc < 4; ++kc) {
        bf16x8 a = *(const bf16x8*)(Aptr + kc * 32);
        size_t boff = (size_t)kc * 4096 + (size_t)lane * 8;
#pragma unroll
        for (int nt = 0; nt < 8; ++nt) {
            bf16x8 b2 = *(const bf16x8*)(Bv + boff + nt * 512);
            av[nt] = __builtin_amdgcn_mfma_f32_16x16x32_bf16(a, b2, av[nt], 0, 0, 0);
            bf16x8 b3 = *(const bf16x8*)(Bs + boff + nt * 512);
            as_[nt] = __builtin_amdgcn_mfma_f32_16x16x32_bf16(a, b3, as_[nt], 0, 0, 0);
        }
    }
    int col0 = lane & 15;
    int r0 = base + (lane >> 4) * 4;
    float4 bvl = *(const float4*)&bv[col0 * 8], bvh = *(const float4*)&bv[col0 * 8 + 4];
    float4 bsl = *(const float4*)&bs[col0 * 8], bsh = *(const float4*)&bs[col0 * 8 + 4];
#pragma unroll
    for (int r = 0; r < 4; ++r) {
        int ro = r0 + r;
        if (ro < M) {
            size_t qo = (size_t)ro * 128 + col0 * 8;
            size_t kvo = (size_t)ro * 256 + 128 + col0 * 8;
            *(uint4*)&kvbf[kvo] = make_uint4(
                f2bf2(av[0][r] + bvl.x, av[1][r] + bvl.y), f2bf2(av[2][r] + bvl.z, av[3][r] + bvl.w),
                f2bf2(av[4][r] + bvh.x, av[5][r] + bvh.y), f2bf2(av[6][r] + bvh.z, av[7][r] + bvh.w));
            *(float4*)&xr[qo]     = make_float4(as_[0][r] + bsl.x, as_[1][r] + bsl.y,
                                                as_[2][r] + bsl.z, as_[3][r] + bsl.w);
            *(float4*)&xr[qo + 4] = make_float4(as_[4][r] + bsh.x, as_[5][r] + bsh.y,
                                                as_[6][r] + bsh.z, as_[7][r] + bsh.w);
        }
    }
}

// ---------- CSR build ----------
__global__ __launch_bounds__(256) void csr_hist(const int* __restrict__ ei,
                                                int* __restrict__ deg, int E) {
    int e = blockIdx.x * 256 + threadIdx.x;
    if (e < E) atomicAdd(&deg[ei[E + e]], 1);
}

__global__ __launch_bounds__(256) void scan_block_sums(const int* __restrict__ deg,
                                                       int* __restrict__ bsums, int N) {
    __shared__ int sd[256];
    int i = blockIdx.x * 256 + threadIdx.x;
    sd[threadIdx.x] = (i < N) ? deg[i] : 0;
    __syncthreads();
    for (int off = 128; off > 0; off >>= 1) {
        if (threadIdx.x < off) sd[threadIdx.x] += sd[threadIdx.x + off];
        __syncthreads();
    }
    if (threadIdx.x == 0) bsums[blockIdx.x] = sd[0];
}

__global__ __launch_bounds__(256) void scan_bsums(const int* __restrict__ bsums,
                                                  int* __restrict__ boff, int nb) {
    __shared__ int sd[256];
    int tid = threadIdx.x;
    int per = (nb + 255) / 256;
    int start = tid * per;
    int s = 0;
    for (int i = 0; i < per; ++i) {
        int idx = start + i;
        if (idx < nb) s += bsums[idx];
    }
    int my = s;
    sd[tid] = s;
    __syncthreads();
    for (int off = 1; off < 256; off <<= 1) {
        int t = (tid >= off) ? sd[tid - off] : 0;
        __syncthreads();
        sd[tid] += t;
        __syncthreads();
    }
    int run = sd[tid] - my;
    for (int i = 0; i < per; ++i) {
        int idx = start + i;
        if (idx < nb) {
            boff[idx] = run;
            run += bsums[idx];
        }
    }
}

__global__ __launch_bounds__(256) void scan_local(const int* __restrict__ deg,
                                                  const int* __restrict__ boff,
                                                  int* __restrict__ rowptr,
                                                  int* __restrict__ wrptr, int N, int E) {
    __shared__ int sd[256];
    int i = blockIdx.x * 256 + threadIdx.x;
    int v = (i < N) ? deg[i] : 0;
    sd[threadIdx.x] = v;
    __syncthreads();
    for (int off = 1; off < 256; off <<= 1) {
        int t = (threadIdx.x >= off) ? sd[threadIdx.x - off] : 0;
        __syncthreads();
        sd[threadIdx.x] += t;
        __syncthreads();
    }
    if (i < N) {
        int excl = sd[threadIdx.x] - v + boff[blockIdx.x];
        rowptr[i] = excl;
        wrptr[i] = excl;
        if (i == N - 1) rowptr[N] = E;
    }
}

// (src, w) packed as int2: one 8B store here, one 8B load per edge in attn.
__global__ __launch_bounds__(256) void csr_fill(const int* __restrict__ ei,
                                                const float* __restrict__ ea,
                                                int* __restrict__ wrptr,
                                                int2* __restrict__ csr_sw, int E) {
    int e = blockIdx.x * 256 + threadIdx.x;
    if (e >= E) return;
    int tgt = ei[E + e];
    int pos = atomicAdd(&wrptr[tgt], 1);
    csr_sw[pos] = make_int2(ei[e], __float_as_int(ea[e]));
}

// ---------- attention gather v5: 16 lanes/node, depth-2 kv pipeline + fused BN stats ----------
// sw (src,w) kept resident for edges i..i+3; kv rows for i..i+3 in flight.
// No sw->kv dependent chain inside the loop.
__global__ __launch_bounds__(256) void attn_gather(const unsigned short* __restrict__ qbf,
                                                   const unsigned short* __restrict__ kvbf,
                                                   const float* __restrict__ xr,
                                                   const int* __restrict__ rowptr,
                                                   const int2* __restrict__ csr_sw,
                                                   const float* __restrict__ Wel,
                                                   const float* __restrict__ Wb,
                                                   float* __restrict__ out,
                                                   float* __restrict__ bsumR,
                                                   float* __restrict__ bsumsqR, int N) {
    __shared__ float sdS[4][128];
    __shared__ float sdQ[4][128];
    int tid = threadIdx.x;
    int n = blockIdx.x * 16 + (tid >> 4);
    int sl = tid & 15;
    int wave = tid >> 6, lane = tid & 63;
    bool live = (n < N);
    int nn = live ? n : (N - 1);

    uint4 qu = ((const uint4*)(qbf + (size_t)nn * 128))[sl];
    float qf[8];
    bfu2(qu.x, qf[0], qf[1]); bfu2(qu.y, qf[2], qf[3]);
    bfu2(qu.z, qf[4], qf[5]); bfu2(qu.w, qf[6], qf[7]);
    float wef[8];
    {
        float4 w0 = ((const float4*)Wel)[sl * 2];
        float4 w1 = ((const float4*)Wel)[sl * 2 + 1];
        wef[0] = w0.x; wef[1] = w0.y; wef[2] = w0.z; wef[3] = w0.w;
        wef[4] = w1.x; wef[5] = w1.y; wef[6] = w1.z; wef[7] = w1.w;
    }
    float qwe = 0.f;
#pragma unroll
    for (int c = 0; c < 8; ++c) qwe += qf[c] * wef[c];
    qwe += __shfl_xor(qwe, 1);
    qwe += __shfl_xor(qwe, 2);

    float l = 0.f;
    float acc[8];
#pragma unroll
    for (int c = 0; c < 8; ++c) acc[c] = 0.f;

    int beg = live ? rowptr[nn] : 0;
    int end = live ? rowptr[nn + 1] : 0;

    if (beg < end) {
        int j1 = (beg + 1 < end) ? beg + 1 : beg;
        int j2 = (beg + 2 < end) ? beg + 2 : beg;
        int j3 = (beg + 3 < end) ? beg + 3 : beg;
        int2 swA = csr_sw[beg], swB = csr_sw[j1];
        int2 swC = csr_sw[j2], swD = csr_sw[j3];
        const uint4* rA = (const uint4*)(kvbf + (size_t)swA.x * 256);
        uint4 ku0 = rA[sl], vu0 = rA[16 + sl];
        const uint4* rB = (const uint4*)(kvbf + (size_t)swB.x * 256);
        uint4 ku1 = rB[sl], vu1 = rB[16 + sl];

        for (int i = beg; i < end; i += 2) {
            // kv prefetch for i+2 / i+3 (addresses already resident -> issue immediately)
            const uint4* rC = (const uint4*)(kvbf + (size_t)swC.x * 256);
            uint4 ku2 = rC[sl], vu2 = rC[16 + sl];
            const uint4* rD = (const uint4*)(kvbf + (size_t)swD.x * 256);
            uint4 ku3 = rD[sl], vu3 = rD[16 + sl];
            // sw prefetch for i+4 / i+5
            int j4 = (i + 4 < end) ? i + 4 : beg;
            int j5 = (i + 5 < end) ? i + 5 : beg;
            int2 swE = csr_sw[j4], swF = csr_sw[j5];

            // ---- edge i (always valid) ----
            {
                float w = __int_as_float(swA.y);
                float kf[8];
                bfu2(ku0.x, kf[0], kf[1]); bfu2(ku0.y, kf[2], kf[3]);
                bfu2(ku0.z, kf[4], kf[5]); bfu2(ku0.w, kf[6], kf[7]);
                float d = 0.f;
#pragma unroll
                for (int c = 0; c < 8; ++c) d += qf[c] * kf[c];
                d += __shfl_xor(d, 1); d += __shfl_xor(d, 2);
                float p = __expf((d + w * qwe) * 0.17677669529663687f);
                l += p;
                float vf[8];
                bfu2(vu0.x, vf[0], vf[1]); bfu2(vu0.y, vf[2], vf[3]);
                bfu2(vu0.z, vf[4], vf[5]); bfu2(vu0.w, vf[6], vf[7]);
#pragma unroll
                for (int c = 0; c < 8; ++c)
                    acc[c] += p * (vf[c] + w * wef[c]);
            }
            // ---- edge i+1 (masked if past end) ----
            {
                float w = __int_as_float(swB.y);
                float kf[8];
                bfu2(ku1.x, kf[0], kf[1]); bfu2(ku1.y, kf[2], kf[3]);
                bfu2(ku1.z, kf[4], kf[5]); bfu2(ku1.w, kf[6], kf[7]);
                float d = 0.f;
#pragma unroll
                for (int c = 0; c < 8; ++c) d += qf[c] * kf[c];
                d += __shfl_xor(d, 1); d += __shfl_xor(d, 2);
                float p = __expf((d + w * qwe) * 0.17677669529663687f);
                if (i + 1 >= end) p = 0.f;
                l += p;
                float vf[8];
                bfu2(vu1.x, vf[0], vf[1]); bfu2(vu1.y, vf[2], vf[3]);
                bfu2(vu1.z, vf[4], vf[5]); bfu2(vu1.w, vf[6], vf[7]);
#pragma unroll
                for (int c = 0; c < 8; ++c)
                    acc[c] += p * (vf[c] + w * wef[c]);
            }
            swA = swC; swB = swD; swC = swE; swD = swF;
            ku0 = ku2; vu0 = vu2; ku1 = ku3; vu1 = vu3;
        }
    }

    float inv = (l > 0.f) ? 1.f / l : 0.f;
    float ox[8];
#pragma unroll
    for (int c = 0; c < 8; ++c) ox[c] = acc[c] * inv;

    const float* xrow = xr + (size_t)nn * 128;
    float4 a0 = ((const float4*)xrow)[sl * 2];
    float4 a1 = ((const float4*)xrow)[sl * 2 + 1];
    float xv[8] = {a0.x, a0.y, a0.z, a0.w, a1.x, a1.y, a1.z, a1.w};
    float4 b0 = ((const float4*)Wb)[sl * 2];
    float4 b1 = ((const float4*)Wb)[sl * 2 + 1];
    float4 c0 = ((const float4*)(Wb + 128))[sl * 2];
    float4 c1 = ((const float4*)(Wb + 128))[sl * 2 + 1];
    float4 d0 = ((const float4*)(Wb + 256))[sl * 2];
    float4 d1 = ((const float4*)(Wb + 256))[sl * 2 + 1];
    float wb0[8] = {b0.x, b0.y, b0.z, b0.w, b1.x, b1.y, b1.z, b1.w};
    float wb1[8] = {c0.x, c0.y, c0.z, c0.w, c1.x, c1.y, c1.z, c1.w};
    float wb2[8] = {d0.x, d0.y, d0.z, d0.w, d1.x, d1.y, d1.z, d1.w};
    float part = 0.f;
#pragma unroll
    for (int c = 0; c < 8; ++c)
        part += ox[c] * wb0[c] + xv[c] * wb1[c] + (ox[c] - xv[c]) * wb2[c];
    part += __shfl_xor(part, 1); part += __shfl_xor(part, 2);
    part += __shfl_xor(part, 4); part += __shfl_xor(part, 8);
    float beta = 1.f / (1.f + __expf(-part));

    float r[8];
#pragma unroll
    for (int c = 0; c < 8; ++c)
        r[c] = beta * xv[c] + (1.f - beta) * ox[c];

    if (live) {
        ((float4*)(out + (size_t)n * 128))[sl * 2] =
            make_float4(r[0], r[1], r[2], r[3]);
        ((float4*)(out + (size_t)n * 128))[sl * 2 + 1] =
            make_float4(r[4], r[5], r[6], r[7]);
    }

    // ---- fused BN stats ----
    float s8[8], q8[8];
#pragma unroll
    for (int c = 0; c < 8; ++c) {
        s8[c] = live ? r[c] : 0.f;
        q8[c] = live ? r[c] * r[c] : 0.f;
    }
#pragma unroll
    for (int c = 0; c < 8; ++c) {
        s8[c] += __shfl_xor(s8[c], 16); s8[c] += __shfl_xor(s8[c], 32);
        q8[c] += __shfl_xor(q8[c], 16); q8[c] += __shfl_xor(q8[c], 32);
    }
    if ((lane >> 4) == 0) {
#pragma unroll
        for (int c = 0; c < 8; ++c) {
            sdS[wave][sl * 8 + c] = s8[c];
            sdQ[wave][sl * 8 + c] = q8[c];
        }
    }
    __syncthreads();
    if (tid < 128) {
        float s = sdS[0][tid] + sdS[1][tid] + sdS[2][tid] + sdS[3][tid];
        float q = sdQ[0][tid] + sdQ[1][tid] + sdQ[2][tid] + sdQ[3][tid];
        int rep = blockIdx.x & 7;
        atomicAdd(&bsumR[rep * 128 + tid], s);
        atomicAdd(&bsumsqR[rep * 128 + tid], q);
    }
}

// ---------- BN apply + ReLU + residual (+ optional bf16 side-write), 8-replica stats ----------
__global__ __launch_bounds__(256) void bn_apply(const float* __restrict__ o,
                                                const float* __restrict__ hres,
                                                float* __restrict__ hout,
                                                unsigned short* __restrict__ hout_bf,
                                                const float* __restrict__ bsumR,
                                                const float* __restrict__ bsumsqR,
                                                const float* __restrict__ gamma,
                                                const float* __restrict__ bbeta,
                                                int N, float invN) {
    int i = blockIdx.x * 256 + threadIdx.x;
    if (i >= N * 32) return;
    int c4 = i & 31;
    float4 s = make_float4(0.f, 0.f, 0.f, 0.f), ss = s;
#pragma unroll
    for (int rep = 0; rep < 8; ++rep) {
        float4 sv = ((const float4*)bsumR)[rep * 32 + c4];
        float4 qv = ((const float4*)bsumsqR)[rep * 32 + c4];
        s.x += sv.x; s.y += sv.y; s.z += sv.z; s.w += sv.w;
        ss.x += qv.x; ss.y += qv.y; ss.z += qv.z; ss.w += qv.w;
    }
    float4 g = ((const float4*)gamma)[c4];
    float4 b = ((const float4*)bbeta)[c4];
    float4 ov = ((const float4*)o)[i];
    float4 hr = ((const float4*)hres)[i];
    float4 r;
    { float mu = s.x * invN, var = ss.x * invN - mu * mu;
      r.x = fmaxf((ov.x - mu) * (g.x * rsqrtf(var + EPS)) + b.x, 0.f) + hr.x; }
    { float mu = s.y * invN, var = ss.y * invN - mu * mu;
      r.y = fmaxf((ov.y - mu) * (g.y * rsqrtf(var + EPS)) + b.y, 0.f) + hr.y; }
    { float mu = s.z * invN, var = ss.z * invN - mu * mu;
      r.z = fmaxf((ov.z - mu) * (g.z * rsqrtf(var + EPS)) + b.z, 0.f) + hr.z; }
    { float mu = s.w * invN, var = ss.w * invN - mu * mu;
      r.w = fmaxf((ov.w - mu) * (g.w * rsqrtf(var + EPS)) + b.w, 0.f) + hr.w; }
    ((float4*)hout)[i] = r;
    if (hout_bf) {
        ushort4 ob = make_ushort4(f2bf(r.x), f2bf(r.y), f2bf(r.z), f2bf(r.w));
        ((ushort4*)hout_bf)[i] = ob;
    }
}

extern "C" void kernel_launch(void* const* d_in, const int* in_sizes, int n_in,
                              void* d_out, int out_size, void* d_ws, size_t ws_size,
                              hipStream_t stream) {
    const float* x     = (const float*)d_in[0];
    const int*   ei    = (const int*)d_in[1];
    const float* ea    = (const float*)d_in[2];
    const float* W_in  = (const float*)d_in[3];
    const float* b_in  = (const float*)d_in[4];
    const float* Wq    = (const float*)d_in[5];
    const float* bq    = (const float*)d_in[6];
    const float* Wk    = (const float*)d_in[7];
    const float* bk    = (const float*)d_in[8];
    const float* Wv    = (const float*)d_in[9];
    const float* bv    = (const float*)d_in[10];
    const float* We    = (const float*)d_in[11];
    const float* Wskip = (const float*)d_in[12];
    const float* bskip = (const float*)d_in[13];
    const float* Wbeta = (const float*)d_in[14];
    const float* bn_g  = (const float*)d_in[15];
    const float* bn_b  = (const float*)d_in[16];

    const int N = in_sizes[0] / 128;
    const int E = in_sizes[1] / 2;

    float* ws = (float*)d_ws;
    unsigned short* Bpack = (unsigned short*)ws;           // 9*16384 bf16 = 73728 floats
    size_t off = 73728;
    unsigned short* xbf  = (unsigned short*)(ws + off);               off += (size_t)N * 64;
    unsigned short* hbf  = (unsigned short*)(ws + off);               off += (size_t)N * 64;
    unsigned short* qbf  = (unsigned short*)(ws + off);               off += (size_t)N * 64;
    unsigned short* kvbf = (unsigned short*)(ws + off);               off += (size_t)N * 128;
    float* h    = ws + off;  off += (size_t)N * 128;
    float* xr   = ws + off;  off += (size_t)N * 128;
    float* attn = ws + off;  off += (size_t)N * 128;
    float* bsumR   = ws + off;  off += 1024;               // 8 replicas x 128
    float* bsumsqR = ws + off;  off += 1024;
    int2* csr_sw = (int2*)(ws + off);  off += (size_t)E * 2;
    int* deg     = (int*)(ws + off);
    int* rowptr  = deg + N;
    int* wrptr   = rowptr + (N + 1);
    int* bsums   = wrptr + N;
    int* boff    = bsums + ((N + 255) / 256 + 1);

    dim3 blk(256);
    int gGemm   = (N + 63) / 64;
    int gNode16 = (N + 15) / 16;
    int gEdge   = (E + 255) / 256;
    int gApply  = (N * 32 + 255) / 256;
    int nbScan  = (N + 255) / 256;

    // ---- weight pack + x convert ----
    pack_w9<<<(9 * 16384 + 255) / 256, blk, 0, stream>>>(
        W_in, Wq, Wk, Wv, Wskip, Wq + 16384, Wk + 16384, Wv + 16384, Wskip + 16384, Bpack);
    f32_to_bf16<<<gApply, blk, 0, stream>>>(x, xbf, N * 32);

    // ---- CSR build ----
    hipMemsetAsync(deg, 0, (size_t)N * sizeof(int), stream);
    csr_hist<<<gEdge, blk, 0, stream>>>(ei, deg, E);
    scan_block_sums<<<nbScan, blk, 0, stream>>>(deg, bsums, N);
    scan_bsums<<<1, blk, 0, stream>>>(bsums, boff, nbScan);
    scan_local<<<nbScan, blk, 0, stream>>>(deg, boff, rowptr, wrptr, N, E);
    csr_fill<<<gEdge, blk, 0, stream>>>(ei, ea, wrptr, csr_sw, E);

    // ---- input projection (writes h fp32 + hbf bf16) ----
    gemm_mfma<1, 1><<<gGemm, blk, 0, stream>>>(xbf, Bpack + 0 * 16384, b_in, h, hbf, N);

    for (int l = 0; l < 2; ++l) {
        const unsigned short* Bq = Bpack + (size_t)(1 + l * 4 + 0) * 16384;
        const unsigned short* Bk = Bpack + (size_t)(1 + l * 4 + 1) * 16384;
        const unsigned short* Bv = Bpack + (size_t)(1 + l * 4 + 2) * 16384;
        const unsigned short* Bs = Bpack + (size_t)(1 + l * 4 + 3) * 16384;
        gemm_qk<<<gGemm, blk, 0, stream>>>(hbf, Bq, Bk, bq + l * 128, bk + l * 128,
                                           qbf, kvbf, N);
        gemm_vs<<<gGemm, blk, 0, stream>>>(hbf, Bv, Bs, bv + l * 128, bskip + l * 128,
                                           kvbf, xr, N);
        hipMemsetAsync(bsumR, 0, 2048 * sizeof(float), stream);
        attn_gather<<<gNode16, blk, 0, stream>>>(qbf, kvbf, xr, rowptr, csr_sw,
                                                 We + l * 128, Wbeta + l * 384, attn,
                                                 bsumR, bsumsqR, N);
        bn_apply<<<gApply, blk, 0, stream>>>(attn, h, (l == 1) ? (float*)d_out : h,
                                             (l == 0) ? hbf : (unsigned short*)0,
                                             bsumR, bsumsqR, bn_g + l * 128, bn_b + l * 128,
                                             N, 1.0f / (float)N);
    }
}

// Round 15
// 339.861 us; speedup vs baseline: 1.0320x; 1.0320x over previous
//
#include <hip/hip_runtime.h>
#include <hip/hip_bf16.h>
#include <math.h>

#define EPS 1e-5f

typedef __attribute__((ext_vector_type(8))) short bf16x8;
typedef __attribute__((ext_vector_type(4))) float f32x4;

__device__ __forceinline__ unsigned short f2bf(float f) {
    unsigned u = __float_as_uint(f);
    unsigned r = (u + 0x7FFFu + ((u >> 16) & 1u)) >> 16;   // RNE
    return (unsigned short)r;
}
__device__ __forceinline__ unsigned f2bf2(float lo, float hi) {
    return (unsigned)f2bf(lo) | ((unsigned)f2bf(hi) << 16);
}
__device__ __forceinline__ float bf2f(unsigned short u) {
    return __uint_as_float((unsigned)u << 16);
}
__device__ __forceinline__ void bfu2(unsigned u, float& lo, float& hi) {
    lo = __uint_as_float(u << 16);
    hi = __uint_as_float(u & 0xFFFF0000u);
}

// ---------- weight pack: 9 matrices fp32 [128k x 128n] -> bf16 B-fragment order ----------
// fragment (nt,col0) = W column col0*8+nt -> lane's 8 accs are 8 consecutive channels.
__global__ __launch_bounds__(256) void pack_w9(const float* __restrict__ W0, const float* __restrict__ W1,
                                               const float* __restrict__ W2, const float* __restrict__ W3,
                                               const float* __restrict__ W4, const float* __restrict__ W5,
                                               const float* __restrict__ W6, const float* __restrict__ W7,
                                               const float* __restrict__ W8, unsigned short* __restrict__ out) {
    int t = blockIdx.x * 256 + threadIdx.x;
    if (t >= 9 * 16384) return;
    int mat = t >> 14, r = t & 16383;
    const float* W;
    switch (mat) {
        case 0: W = W0; break; case 1: W = W1; break; case 2: W = W2; break;
        case 3: W = W3; break; case 4: W = W4; break; case 5: W = W5; break;
        case 6: W = W6; break; case 7: W = W7; break; default: W = W8; break;
    }
    int j = r & 7, lane = (r >> 3) & 63, nt = (r >> 9) & 7, kc = r >> 12;
    int k = kc * 32 + (lane >> 4) * 8 + j;
    int n = (lane & 15) * 8 + nt;
    out[t] = f2bf(W[k * 128 + n]);
}

// ---------- fp32 -> bf16 elementwise ----------
__global__ __launch_bounds__(256) void f32_to_bf16(const float* __restrict__ in,
                                                   unsigned short* __restrict__ out, int n4) {
    int i = blockIdx.x * 256 + threadIdx.x;
    if (i >= n4) return;
    float4 v = ((const float4*)in)[i];
    ushort4 o = make_ushort4(f2bf(v.x), f2bf(v.y), f2bf(v.z), f2bf(v.w));
    ((ushort4*)out)[i] = o;
}

// ---------- MFMA GEMM (single matrix, coalesced epilogue) ----------
template <int ACT, int WBF>
__global__ __launch_bounds__(256) void gemm_mfma(const unsigned short* __restrict__ Abf,
                                                 const unsigned short* __restrict__ Bp,
                                                 const float* __restrict__ bias,
                                                 float* __restrict__ C,
                                                 unsigned short* __restrict__ Cbf, int M) {
    int wave = threadIdx.x >> 6, lane = threadIdx.x & 63;
    int base = blockIdx.x * 64 + wave * 16;
    int m = lane & 15, kg = lane >> 4;
    int arow = base + m; if (arow >= M) arow = M - 1;
    const unsigned short* Aptr = Abf + (size_t)arow * 128 + kg * 8;
    f32x4 acc[8];
#pragma unroll
    for (int nt = 0; nt < 8; ++nt) acc[nt] = (f32x4)(0.f);
#pragma unroll
    for (int kc = 0; kc < 4; ++kc) {
        bf16x8 a = *(const bf16x8*)(Aptr + kc * 32);
        const unsigned short* bp = Bp + (size_t)kc * 4096 + (size_t)lane * 8;
#pragma unroll
        for (int nt = 0; nt < 8; ++nt) {
            bf16x8 b = *(const bf16x8*)(bp + nt * 512);
            acc[nt] = __builtin_amdgcn_mfma_f32_16x16x32_bf16(a, b, acc[nt], 0, 0, 0);
        }
    }
    int col0 = lane & 15;
    int r0 = base + (lane >> 4) * 4;
    float4 bl = *(const float4*)&bias[col0 * 8];
    float4 bh = *(const float4*)&bias[col0 * 8 + 4];
#pragma unroll
    for (int r = 0; r < 4; ++r) {
        int ro = r0 + r;
        if (ro < M) {
            float v0 = acc[0][r] + bl.x, v1 = acc[1][r] + bl.y;
            float v2 = acc[2][r] + bl.z, v3 = acc[3][r] + bl.w;
            float v4 = acc[4][r] + bh.x, v5 = acc[5][r] + bh.y;
            float v6 = acc[6][r] + bh.z, v7 = acc[7][r] + bh.w;
            if (ACT) {
                v0 = fmaxf(v0, 0.f); v1 = fmaxf(v1, 0.f); v2 = fmaxf(v2, 0.f); v3 = fmaxf(v3, 0.f);
                v4 = fmaxf(v4, 0.f); v5 = fmaxf(v5, 0.f); v6 = fmaxf(v6, 0.f); v7 = fmaxf(v7, 0.f);
            }
            size_t o = (size_t)ro * 128 + col0 * 8;
            *(float4*)&C[o]     = make_float4(v0, v1, v2, v3);
            *(float4*)&C[o + 4] = make_float4(v4, v5, v6, v7);
            if (WBF)
                *(uint4*)&Cbf[o] = make_uint4(f2bf2(v0, v1), f2bf2(v2, v3),
                                              f2bf2(v4, v5), f2bf2(v6, v7));
        }
    }
}

// ---------- 2-matrix fused GEMM: q -> qbf, k -> kvbf[0..128) (both bf16) ----------
__global__ __launch_bounds__(256) void gemm_qk(const unsigned short* __restrict__ Abf,
                                               const unsigned short* __restrict__ Bq,
                                               const unsigned short* __restrict__ Bk,
                                               const float* __restrict__ bq,
                                               const float* __restrict__ bk,
                                               unsigned short* __restrict__ qbf,
                                               unsigned short* __restrict__ kvbf, int M) {
    int wave = threadIdx.x >> 6, lane = threadIdx.x & 63;
    int base = blockIdx.x * 64 + wave * 16;
    int m = lane & 15, kg = lane >> 4;
    int arow = base + m; if (arow >= M) arow = M - 1;
    const unsigned short* Aptr = Abf + (size_t)arow * 128 + kg * 8;
    f32x4 aq[8], ak[8];
#pragma unroll
    for (int nt = 0; nt < 8; ++nt) { aq[nt] = (f32x4)(0.f); ak[nt] = (f32x4)(0.f); }
#pragma unroll
    for (int kc = 0; kc < 4; ++kc) {
        bf16x8 a = *(const bf16x8*)(Aptr + kc * 32);
        size_t boff = (size_t)kc * 4096 + (size_t)lane * 8;
#pragma unroll
        for (int nt = 0; nt < 8; ++nt) {
            bf16x8 b0 = *(const bf16x8*)(Bq + boff + nt * 512);
            aq[nt] = __builtin_amdgcn_mfma_f32_16x16x32_bf16(a, b0, aq[nt], 0, 0, 0);
            bf16x8 b1 = *(const bf16x8*)(Bk + boff + nt * 512);
            ak[nt] = __builtin_amdgcn_mfma_f32_16x16x32_bf16(a, b1, ak[nt], 0, 0, 0);
        }
    }
    int col0 = lane & 15;
    int r0 = base + (lane >> 4) * 4;
    float4 bql = *(const float4*)&bq[col0 * 8], bqh = *(const float4*)&bq[col0 * 8 + 4];
    float4 bkl = *(const float4*)&bk[col0 * 8], bkh = *(const float4*)&bk[col0 * 8 + 4];
#pragma unroll
    for (int r = 0; r < 4; ++r) {
        int ro = r0 + r;
        if (ro < M) {
            size_t qo = (size_t)ro * 128 + col0 * 8;
            size_t kvo = (size_t)ro * 256 + col0 * 8;
            *(uint4*)&qbf[qo] = make_uint4(
                f2bf2(aq[0][r] + bql.x, aq[1][r] + bql.y), f2bf2(aq[2][r] + bql.z, aq[3][r] + bql.w),
                f2bf2(aq[4][r] + bqh.x, aq[5][r] + bqh.y), f2bf2(aq[6][r] + bqh.z, aq[7][r] + bqh.w));
            *(uint4*)&kvbf[kvo] = make_uint4(
                f2bf2(ak[0][r] + bkl.x, ak[1][r] + bkl.y), f2bf2(ak[2][r] + bkl.z, ak[3][r] + bkl.w),
                f2bf2(ak[4][r] + bkh.x, ak[5][r] + bkh.y), f2bf2(ak[6][r] + bkh.z, ak[7][r] + bkh.w));
        }
    }
}

// ---------- 2-matrix fused GEMM: v -> kvbf[128..256) (bf16), skip -> xr (fp32) ----------
// Block 0 also zeroes the BN-stat replica buffers (replaces 2 memset dispatches;
// stream order guarantees this precedes attn_gather's atomics).
__global__ __launch_bounds__(256) void gemm_vs(const unsigned short* __restrict__ Abf,
                                               const unsigned short* __restrict__ Bv,
                                               const unsigned short* __restrict__ Bs,
                                               const float* __restrict__ bv,
                                               const float* __restrict__ bs,
                                               unsigned short* __restrict__ kvbf,
                                               float* __restrict__ xr,
                                               float* __restrict__ bstatZ, int M) {
    if (blockIdx.x == 0) {
        ((float2*)bstatZ)[threadIdx.x] = make_float2(0.f, 0.f);
        ((float2*)bstatZ)[256 + threadIdx.x] = make_float2(0.f, 0.f);
        ((float2*)bstatZ)[512 + threadIdx.x] = make_float2(0.f, 0.f);
        ((float2*)bstatZ)[768 + threadIdx.x] = make_float2(0.f, 0.f);
    }
    int wave = threadIdx.x >> 6, lane = threadIdx.x & 63;
    int base = blockIdx.x * 64 + wave * 16;
    int m = lane & 15, kg = lane >> 4;
    int arow = base + m; if (arow >= M) arow = M - 1;
    const unsigned short* Aptr = Abf + (size_t)arow * 128 + kg * 8;
    f32x4 av[8], as_[8];
#pragma unroll
    for (int nt = 0; nt < 8; ++nt) { av[nt] = (f32x4)(0.f); as_[nt] = (f32x4)(0.f); }
#pragma unroll
    for (int kc = 0; kc < 4; ++kc) {
        bf16x8 a = *(const bf16x8*)(Aptr + kc * 32);
        size_t boff = (size_t)kc * 4096 + (size_t)lane * 8;
#pragma unroll
        for (int nt = 0; nt < 8; ++nt) {
            bf16x8 b2 = *(const bf16x8*)(Bv + boff + nt * 512);
            av[nt] = __builtin_amdgcn_mfma_f32_16x16x32_bf16(a, b2, av[nt], 0, 0, 0);
            bf16x8 b3 = *(const bf16x8*)(Bs + boff + nt * 512);
            as_[nt] = __builtin_amdgcn_mfma_f32_16x16x32_bf16(a, b3, as_[nt], 0, 0, 0);
        }
    }
    int col0 = lane & 15;
    int r0 = base + (lane >> 4) * 4;
    float4 bvl = *(const float4*)&bv[col0 * 8], bvh = *(const float4*)&bv[col0 * 8 + 4];
    float4 bsl = *(const float4*)&bs[col0 * 8], bsh = *(const float4*)&bs[col0 * 8 + 4];
#pragma unroll
    for (int r = 0; r < 4; ++r) {
        int ro = r0 + r;
        if (ro < M) {
            size_t qo = (size_t)ro * 128 + col0 * 8;
            size_t kvo = (size_t)ro * 256 + 128 + col0 * 8;
            *(uint4*)&kvbf[kvo] = make_uint4(
                f2bf2(av[0][r] + bvl.x, av[1][r] + bvl.y), f2bf2(av[2][r] + bvl.z, av[3][r] + bvl.w),
                f2bf2(av[4][r] + bvh.x, av[5][r] + bvh.y), f2bf2(av[6][r] + bvh.z, av[7][r] + bvh.w));
            *(float4*)&xr[qo]     = make_float4(as_[0][r] + bsl.x, as_[1][r] + bsl.y,
                                                as_[2][r] + bsl.z, as_[3][r] + bsl.w);
            *(float4*)&xr[qo + 4] = make_float4(as_[4][r] + bsh.x, as_[5][r] + bsh.y,
                                                as_[6][r] + bsh.z, as_[7][r] + bsh.w);
        }
    }
}

// ---------- CSR build ----------
__global__ __launch_bounds__(256) void csr_hist(const int* __restrict__ ei,
                                                int* __restrict__ deg, int E) {
    int e = blockIdx.x * 256 + threadIdx.x;
    if (e < E) atomicAdd(&deg[ei[E + e]], 1);
}

__global__ __launch_bounds__(256) void scan_block_sums(const int* __restrict__ deg,
                                                       int* __restrict__ bsums, int N) {
    __shared__ int sd[256];
    int i = blockIdx.x * 256 + threadIdx.x;
    sd[threadIdx.x] = (i < N) ? deg[i] : 0;
    __syncthreads();
    for (int off = 128; off > 0; off >>= 1) {
        if (threadIdx.x < off) sd[threadIdx.x] += sd[threadIdx.x + off];
        __syncthreads();
    }
    if (threadIdx.x == 0) bsums[blockIdx.x] = sd[0];
}

__global__ __launch_bounds__(256) void scan_bsums(const int* __restrict__ bsums,
                                                  int* __restrict__ boff, int nb) {
    __shared__ int sd[256];
    int tid = threadIdx.x;
    int per = (nb + 255) / 256;
    int start = tid * per;
    int s = 0;
    for (int i = 0; i < per; ++i) {
        int idx = start + i;
        if (idx < nb) s += bsums[idx];
    }
    int my = s;
    sd[tid] = s;
    __syncthreads();
    for (int off = 1; off < 256; off <<= 1) {
        int t = (tid >= off) ? sd[tid - off] : 0;
        __syncthreads();
        sd[tid] += t;
        __syncthreads();
    }
    int run = sd[tid] - my;
    for (int i = 0; i < per; ++i) {
        int idx = start + i;
        if (idx < nb) {
            boff[idx] = run;
            run += bsums[idx];
        }
    }
}

__global__ __launch_bounds__(256) void scan_local(const int* __restrict__ deg,
                                                  const int* __restrict__ boff,
                                                  int* __restrict__ rowptr,
                                                  int* __restrict__ wrptr, int N, int E) {
    __shared__ int sd[256];
    int i = blockIdx.x * 256 + threadIdx.x;
    int v = (i < N) ? deg[i] : 0;
    sd[threadIdx.x] = v;
    __syncthreads();
    for (int off = 1; off < 256; off <<= 1) {
        int t = (threadIdx.x >= off) ? sd[threadIdx.x - off] : 0;
        __syncthreads();
        sd[threadIdx.x] += t;
        __syncthreads();
    }
    if (i < N) {
        int excl = sd[threadIdx.x] - v + boff[blockIdx.x];
        rowptr[i] = excl;
        wrptr[i] = excl;
        if (i == N - 1) rowptr[N] = E;
    }
}

// (src, w) packed as int2: one 8B store here, one 8B load per edge in attn.
__global__ __launch_bounds__(256) void csr_fill(const int* __restrict__ ei,
                                                const float* __restrict__ ea,
                                                int* __restrict__ wrptr,
                                                int2* __restrict__ csr_sw, int E) {
    int e = blockIdx.x * 256 + threadIdx.x;
    if (e >= E) return;
    int tgt = ei[E + e];
    int pos = atomicAdd(&wrptr[tgt], 1);
    csr_sw[pos] = make_int2(ei[e], __float_as_int(ea[e]));
}

// ---------- attention gather v6: 16 lanes/node, 1 edge/iter, sw 2-ahead / kv 1-ahead ----------
__global__ __launch_bounds__(256) void attn_gather(const unsigned short* __restrict__ qbf,
                                                   const unsigned short* __restrict__ kvbf,
                                                   const float* __restrict__ xr,
                                                   const int* __restrict__ rowptr,
                                                   const int2* __restrict__ csr_sw,
                                                   const float* __restrict__ Wel,
                                                   const float* __restrict__ Wb,
                                                   float* __restrict__ out,
                                                   float* __restrict__ bsumR,
                                                   float* __restrict__ bsumsqR, int N) {
    __shared__ float sdS[4][128];
    __shared__ float sdQ[4][128];
    int tid = threadIdx.x;
    int n = blockIdx.x * 16 + (tid >> 4);
    int sl = tid & 15;
    int wave = tid >> 6, lane = tid & 63;
    bool live = (n < N);
    int nn = live ? n : (N - 1);

    uint4 qu = ((const uint4*)(qbf + (size_t)nn * 128))[sl];
    float qf[8];
    bfu2(qu.x, qf[0], qf[1]); bfu2(qu.y, qf[2], qf[3]);
    bfu2(qu.z, qf[4], qf[5]); bfu2(qu.w, qf[6], qf[7]);
    float wef[8];
    {
        float4 w0 = ((const float4*)Wel)[sl * 2];
        float4 w1 = ((const float4*)Wel)[sl * 2 + 1];
        wef[0] = w0.x; wef[1] = w0.y; wef[2] = w0.z; wef[3] = w0.w;
        wef[4] = w1.x; wef[5] = w1.y; wef[6] = w1.z; wef[7] = w1.w;
    }
    float qwe = 0.f;
#pragma unroll
    for (int c = 0; c < 8; ++c) qwe += qf[c] * wef[c];
    qwe += __shfl_xor(qwe, 1);
    qwe += __shfl_xor(qwe, 2);

    float l = 0.f;
    float acc[8];
#pragma unroll
    for (int c = 0; c < 8; ++c) acc[c] = 0.f;

    int beg = live ? rowptr[nn] : 0;
    int end = live ? rowptr[nn + 1] : 0;

    if (beg < end) {
        int2 sw0 = csr_sw[beg];                               // edge i
        int j1 = (beg + 1 < end) ? beg + 1 : beg;
        int2 sw1 = csr_sw[j1];                                // edge i+1
        const uint4* r0 = (const uint4*)(kvbf + (size_t)sw0.x * 256);
        uint4 ku = r0[sl], vu = r0[16 + sl];

        for (int i = beg; i < end; ++i) {
            // kv for edge i+1 — address already resident, issues immediately
            const uint4* r1 = (const uint4*)(kvbf + (size_t)sw1.x * 256);
            uint4 kun = r1[sl], vun = r1[16 + sl];
            // sw for edge i+2
            int j2 = (i + 2 < end) ? i + 2 : beg;
            int2 sw2 = csr_sw[j2];

            float w = __int_as_float(sw0.y);
            float kf[8];
            bfu2(ku.x, kf[0], kf[1]); bfu2(ku.y, kf[2], kf[3]);
            bfu2(ku.z, kf[4], kf[5]); bfu2(ku.w, kf[6], kf[7]);
            float d = 0.f;
#pragma unroll
            for (int c = 0; c < 8; ++c) d += qf[c] * kf[c];
            d += __shfl_xor(d, 1); d += __shfl_xor(d, 2);
            float p = __expf((d + w * qwe) * 0.17677669529663687f);
            l += p;
            float vf[8];
            bfu2(vu.x, vf[0], vf[1]); bfu2(vu.y, vf[2], vf[3]);
            bfu2(vu.z, vf[4], vf[5]); bfu2(vu.w, vf[6], vf[7]);
#pragma unroll
            for (int c = 0; c < 8; ++c)
                acc[c] += p * (vf[c] + w * wef[c]);

            sw0 = sw1; sw1 = sw2;
            ku = kun; vu = vun;
        }
    }

    float inv = (l > 0.f) ? 1.f / l : 0.f;
    float ox[8];
#pragma unroll
    for (int c = 0; c < 8; ++c) ox[c] = acc[c] * inv;

    const float* xrow = xr + (size_t)nn * 128;
    float4 a0 = ((const float4*)xrow)[sl * 2];
    float4 a1 = ((const float4*)xrow)[sl * 2 + 1];
    float xv[8] = {a0.x, a0.y, a0.z, a0.w, a1.x, a1.y, a1.z, a1.w};
    float4 b0 = ((const float4*)Wb)[sl * 2];
    float4 b1 = ((const float4*)Wb)[sl * 2 + 1];
    float4 c0 = ((const float4*)(Wb + 128))[sl * 2];
    float4 c1 = ((const float4*)(Wb + 128))[sl * 2 + 1];
    float4 d0 = ((const float4*)(Wb + 256))[sl * 2];
    float4 d1 = ((const float4*)(Wb + 256))[sl * 2 + 1];
    float wb0[8] = {b0.x, b0.y, b0.z, b0.w, b1.x, b1.y, b1.z, b1.w};
    float wb1[8] = {c0.x, c0.y, c0.z, c0.w, c1.x, c1.y, c1.z, c1.w};
    float wb2[8] = {d0.x, d0.y, d0.z, d0.w, d1.x, d1.y, d1.z, d1.w};
    float part = 0.f;
#pragma unroll
    for (int c = 0; c < 8; ++c)
        part += ox[c] * wb0[c] + xv[c] * wb1[c] + (ox[c] - xv[c]) * wb2[c];
    part += __shfl_xor(part, 1); part += __shfl_xor(part, 2);
    part += __shfl_xor(part, 4); part += __shfl_xor(part, 8);
    float beta = 1.f / (1.f + __expf(-part));

    float r[8];
#pragma unroll
    for (int c = 0; c < 8; ++c)
        r[c] = beta * xv[c] + (1.f - beta) * ox[c];

    if (live) {
        ((float4*)(out + (size_t)n * 128))[sl * 2] =
            make_float4(r[0], r[1], r[2], r[3]);
        ((float4*)(out + (size_t)n * 128))[sl * 2 + 1] =
            make_float4(r[4], r[5], r[6], r[7]);
    }

    // ---- fused BN stats ----
    float s8[8], q8[8];
#pragma unroll
    for (int c = 0; c < 8; ++c) {
        s8[c] = live ? r[c] : 0.f;
        q8[c] = live ? r[c] * r[c] : 0.f;
    }
#pragma unroll
    for (int c = 0; c < 8; ++c) {
        s8[c] += __shfl_xor(s8[c], 16); s8[c] += __shfl_xor(s8[c], 32);
        q8[c] += __shfl_xor(q8[c], 16); q8[c] += __shfl_xor(q8[c], 32);
    }
    if ((lane >> 4) == 0) {
#pragma unroll
        for (int c = 0; c < 8; ++c) {
            sdS[wave][sl * 8 + c] = s8[c];
            sdQ[wave][sl * 8 + c] = q8[c];
        }
    }
    __syncthreads();
    if (tid < 128) {
        float s = sdS[0][tid] + sdS[1][tid] + sdS[2][tid] + sdS[3][tid];
        float q = sdQ[0][tid] + sdQ[1][tid] + sdQ[2][tid] + sdQ[3][tid];
        int rep = blockIdx.x & 7;
        atomicAdd(&bsumR[rep * 128 + tid], s);
        atomicAdd(&bsumsqR[rep * 128 + tid], q);
    }
}

// ---------- BN apply + ReLU + residual (+ optional bf16 side-write), 8-replica stats ----------
__global__ __launch_bounds__(256) void bn_apply(const float* __restrict__ o,
                                                const float* __restrict__ hres,
                                                float* __restrict__ hout,
                                                unsigned short* __restrict__ hout_bf,
                                                const float* __restrict__ bsumR,
                                                const float* __restrict__ bsumsqR,
                                                const float* __restrict__ gamma,
                                                const float* __restrict__ bbeta,
                                                int N, float invN) {
    int i = blockIdx.x * 256 + threadIdx.x;
    if (i >= N * 32) return;
    int c4 = i & 31;
    float4 s = make_float4(0.f, 0.f, 0.f, 0.f), ss = s;
#pragma unroll
    for (int rep = 0; rep < 8; ++rep) {
        float4 sv = ((const float4*)bsumR)[rep * 32 + c4];
        float4 qv = ((const float4*)bsumsqR)[rep * 32 + c4];
        s.x += sv.x; s.y += sv.y; s.z += sv.z; s.w += sv.w;
        ss.x += qv.x; ss.y += qv.y; ss.z += qv.z; ss.w += qv.w;
    }
    float4 g = ((const float4*)gamma)[c4];
    float4 b = ((const float4*)bbeta)[c4];
    float4 ov = ((const float4*)o)[i];
    float4 hr = ((const float4*)hres)[i];
    float4 r;
    { float mu = s.x * invN, var = ss.x * invN - mu * mu;
      r.x = fmaxf((ov.x - mu) * (g.x * rsqrtf(var + EPS)) + b.x, 0.f) + hr.x; }
    { float mu = s.y * invN, var = ss.y * invN - mu * mu;
      r.y = fmaxf((ov.y - mu) * (g.y * rsqrtf(var + EPS)) + b.y, 0.f) + hr.y; }
    { float mu = s.z * invN, var = ss.z * invN - mu * mu;
      r.z = fmaxf((ov.z - mu) * (g.z * rsqrtf(var + EPS)) + b.z, 0.f) + hr.z; }
    { float mu = s.w * invN, var = ss.w * invN - mu * mu;
      r.w = fmaxf((ov.w - mu) * (g.w * rsqrtf(var + EPS)) + b.w, 0.f) + hr.w; }
    ((float4*)hout)[i] = r;
    if (hout_bf) {
        ushort4 ob = make_ushort4(f2bf(r.x), f2bf(r.y), f2bf(r.z), f2bf(r.w));
        ((ushort4*)hout_bf)[i] = ob;
    }
}

extern "C" void kernel_launch(void* const* d_in, const int* in_sizes, int n_in,
                              void* d_out, int out_size, void* d_ws, size_t ws_size,
                              hipStream_t stream) {
    const float* x     = (const float*)d_in[0];
    const int*   ei    = (const int*)d_in[1];
    const float* ea    = (const float*)d_in[2];
    const float* W_in  = (const float*)d_in[3];
    const float* b_in  = (const float*)d_in[4];
    const float* Wq    = (const float*)d_in[5];
    const float* bq    = (const float*)d_in[6];
    const float* Wk    = (const float*)d_in[7];
    const float* bk    = (const float*)d_in[8];
    const float* Wv    = (const float*)d_in[9];
    const float* bv    = (const float*)d_in[10];
    const float* We    = (const float*)d_in[11];
    const float* Wskip = (const float*)d_in[12];
    const float* bskip = (const float*)d_in[13];
    const float* Wbeta = (const float*)d_in[14];
    const float* bn_g  = (const float*)d_in[15];
    const float* bn_b  = (const float*)d_in[16];

    const int N = in_sizes[0] / 128;
    const int E = in_sizes[1] / 2;

    float* ws = (float*)d_ws;
    unsigned short* Bpack = (unsigned short*)ws;           // 9*16384 bf16 = 73728 floats
    size_t off = 73728;
    unsigned short* xbf  = (unsigned short*)(ws + off);               off += (size_t)N * 64;
    unsigned short* hbf  = (unsigned short*)(ws + off);               off += (size_t)N * 64;
    unsigned short* qbf  = (unsigned short*)(ws + off);               off += (size_t)N * 64;
    unsigned short* kvbf = (unsigned short*)(ws + off);               off += (size_t)N * 128;
    float* h    = ws + off;  off += (size_t)N * 128;
    float* xr   = ws + off;  off += (size_t)N * 128;
    float* attn = ws + off;  off += (size_t)N * 128;
    float* bsumR   = ws + off;  off += 1024;               // 8 replicas x 128
    float* bsumsqR = ws + off;  off += 1024;               // contiguous after bsumR
    int2* csr_sw = (int2*)(ws + off);  off += (size_t)E * 2;
    int* deg     = (int*)(ws + off);
    int* rowptr  = deg + N;
    int* wrptr   = rowptr + (N + 1);
    int* bsums   = wrptr + N;
    int* boff    = bsums + ((N + 255) / 256 + 1);

    dim3 blk(256);
    int gGemm   = (N + 63) / 64;
    int gNode16 = (N + 15) / 16;
    int gEdge   = (E + 255) / 256;
    int gApply  = (N * 32 + 255) / 256;
    int nbScan  = (N + 255) / 256;

    // ---- weight pack + x convert ----
    pack_w9<<<(9 * 16384 + 255) / 256, blk, 0, stream>>>(
        W_in, Wq, Wk, Wv, Wskip, Wq + 16384, Wk + 16384, Wv + 16384, Wskip + 16384, Bpack);
    f32_to_bf16<<<gApply, blk, 0, stream>>>(x, xbf, N * 32);

    // ---- CSR build ----
    hipMemsetAsync(deg, 0, (size_t)N * sizeof(int), stream);
    csr_hist<<<gEdge, blk, 0, stream>>>(ei, deg, E);
    scan_block_sums<<<nbScan, blk, 0, stream>>>(deg, bsums, N);
    scan_bsums<<<1, blk, 0, stream>>>(bsums, boff, nbScan);
    scan_local<<<nbScan, blk, 0, stream>>>(deg, boff, rowptr, wrptr, N, E);
    csr_fill<<<gEdge, blk, 0, stream>>>(ei, ea, wrptr, csr_sw, E);

    // ---- input projection (writes h fp32 + hbf bf16) ----
    gemm_mfma<1, 1><<<gGemm, blk, 0, stream>>>(xbf, Bpack + 0 * 16384, b_in, h, hbf, N);

    for (int l = 0; l < 2; ++l) {
        const unsigned short* Bq = Bpack + (size_t)(1 + l * 4 + 0) * 16384;
        const unsigned short* Bk = Bpack + (size_t)(1 + l * 4 + 1) * 16384;
        const unsigned short* Bv = Bpack + (size_t)(1 + l * 4 + 2) * 16384;
        const unsigned short* Bs = Bpack + (size_t)(1 + l * 4 + 3) * 16384;
        gemm_qk<<<gGemm, blk, 0, stream>>>(hbf, Bq, Bk, bq + l * 128, bk + l * 128,
                                           qbf, kvbf, N);
        gemm_vs<<<gGemm, blk, 0, stream>>>(hbf, Bv, Bs, bv + l * 128, bskip + l * 128,
                                           kvbf, xr, bsumR, N);
        attn_gather<<<gNode16, blk, 0, stream>>>(qbf, kvbf, xr, rowptr, csr_sw,
                                                 We + l * 128, Wbeta + l * 384, attn,
                                                 bsumR, bsumsqR, N);
        bn_apply<<<gApply, blk, 0, stream>>>(attn, h, (l == 1) ? (float*)d_out : h,
                                             (l == 0) ? hbf : (unsigned short*)0,
                                             bsumR, bsumsqR, bn_g + l * 128, bn_b + l * 128,
                                             N, 1.0f / (float)N);
    }
}

// Round 16
// 336.860 us; speedup vs baseline: 1.0412x; 1.0089x over previous
//
#include <hip/hip_runtime.h>
#include <hip/hip_bf16.h>
#include <math.h>

#define EPS 1e-5f

typedef __attribute__((ext_vector_type(8))) short bf16x8;
typedef __attribute__((ext_vector_type(4))) float f32x4;

__device__ __forceinline__ unsigned short f2bf(float f) {
    unsigned u = __float_as_uint(f);
    unsigned r = (u + 0x7FFFu + ((u >> 16) & 1u)) >> 16;   // RNE
    return (unsigned short)r;
}
__device__ __forceinline__ unsigned f2bf2(float lo, float hi) {
    return (unsigned)f2bf(lo) | ((unsigned)f2bf(hi) << 16);
}
__device__ __forceinline__ float bf2f(unsigned short u) {
    return __uint_as_float((unsigned)u << 16);
}
__device__ __forceinline__ void bfu2(unsigned u, float& lo, float& hi) {
    lo = __uint_as_float(u << 16);
    hi = __uint_as_float(u & 0xFFFF0000u);
}

// ---------- fused prep: x->bf16 | weight pack | deg zero (3 dispatches -> 1) ----------
// fragment (nt,col0) = W column col0*8+nt -> lane's 8 accs are 8 consecutive channels.
__global__ __launch_bounds__(256) void prep(const float* __restrict__ x,
                                            unsigned short* __restrict__ xbf, int n4,
                                            const float* __restrict__ W0, const float* __restrict__ W1,
                                            const float* __restrict__ W2, const float* __restrict__ W3,
                                            const float* __restrict__ W4, const float* __restrict__ W5,
                                            const float* __restrict__ W6, const float* __restrict__ W7,
                                            const float* __restrict__ W8, unsigned short* __restrict__ Bpack,
                                            int* __restrict__ deg, int N,
                                            int nConv, int nPack) {
    int b = blockIdx.x;
    if (b < nConv) {
        int i = b * 256 + threadIdx.x;
        if (i < n4) {
            float4 v = ((const float4*)x)[i];
            ushort4 o = make_ushort4(f2bf(v.x), f2bf(v.y), f2bf(v.z), f2bf(v.w));
            ((ushort4*)xbf)[i] = o;
        }
    } else if (b < nConv + nPack) {
        int t = (b - nConv) * 256 + threadIdx.x;
        if (t < 9 * 16384) {
            int mat = t >> 14, r = t & 16383;
            const float* W;
            switch (mat) {
                case 0: W = W0; break; case 1: W = W1; break; case 2: W = W2; break;
                case 3: W = W3; break; case 4: W = W4; break; case 5: W = W5; break;
                case 6: W = W6; break; case 7: W = W7; break; default: W = W8; break;
            }
            int j = r & 7, lane = (r >> 3) & 63, nt = (r >> 9) & 7, kc = r >> 12;
            int k = kc * 32 + (lane >> 4) * 8 + j;
            int n = (lane & 15) * 8 + nt;
            Bpack[t] = f2bf(W[k * 128 + n]);
        }
    } else {
        int i = (b - nConv - nPack) * 256 + threadIdx.x;
        if (i < N) deg[i] = 0;
    }
}

// ---------- MFMA GEMM (single matrix, coalesced epilogue) ----------
template <int ACT, int WBF>
__global__ __launch_bounds__(256) void gemm_mfma(const unsigned short* __restrict__ Abf,
                                                 const unsigned short* __restrict__ Bp,
                                                 const float* __restrict__ bias,
                                                 float* __restrict__ C,
                                                 unsigned short* __restrict__ Cbf, int M) {
    int wave = threadIdx.x >> 6, lane = threadIdx.x & 63;
    int base = blockIdx.x * 64 + wave * 16;
    int m = lane & 15, kg = lane >> 4;
    int arow = base + m; if (arow >= M) arow = M - 1;
    const unsigned short* Aptr = Abf + (size_t)arow * 128 + kg * 8;
    f32x4 acc[8];
#pragma unroll
    for (int nt = 0; nt < 8; ++nt) acc[nt] = (f32x4)(0.f);
#pragma unroll
    for (int kc = 0; kc < 4; ++kc) {
        bf16x8 a = *(const bf16x8*)(Aptr + kc * 32);
        const unsigned short* bp = Bp + (size_t)kc * 4096 + (size_t)lane * 8;
#pragma unroll
        for (int nt = 0; nt < 8; ++nt) {
            bf16x8 b = *(const bf16x8*)(bp + nt * 512);
            acc[nt] = __builtin_amdgcn_mfma_f32_16x16x32_bf16(a, b, acc[nt], 0, 0, 0);
        }
    }
    int col0 = lane & 15;
    int r0 = base + (lane >> 4) * 4;
    float4 bl = *(const float4*)&bias[col0 * 8];
    float4 bh = *(const float4*)&bias[col0 * 8 + 4];
#pragma unroll
    for (int r = 0; r < 4; ++r) {
        int ro = r0 + r;
        if (ro < M) {
            float v0 = acc[0][r] + bl.x, v1 = acc[1][r] + bl.y;
            float v2 = acc[2][r] + bl.z, v3 = acc[3][r] + bl.w;
            float v4 = acc[4][r] + bh.x, v5 = acc[5][r] + bh.y;
            float v6 = acc[6][r] + bh.z, v7 = acc[7][r] + bh.w;
            if (ACT) {
                v0 = fmaxf(v0, 0.f); v1 = fmaxf(v1, 0.f); v2 = fmaxf(v2, 0.f); v3 = fmaxf(v3, 0.f);
                v4 = fmaxf(v4, 0.f); v5 = fmaxf(v5, 0.f); v6 = fmaxf(v6, 0.f); v7 = fmaxf(v7, 0.f);
            }
            size_t o = (size_t)ro * 128 + col0 * 8;
            *(float4*)&C[o]     = make_float4(v0, v1, v2, v3);
            *(float4*)&C[o + 4] = make_float4(v4, v5, v6, v7);
            if (WBF)
                *(uint4*)&Cbf[o] = make_uint4(f2bf2(v0, v1), f2bf2(v2, v3),
                                              f2bf2(v4, v5), f2bf2(v6, v7));
        }
    }
}

// ---------- 2-matrix fused GEMM: q -> qbf, k -> kvbf[0..128) (both bf16) ----------
__global__ __launch_bounds__(256) void gemm_qk(const unsigned short* __restrict__ Abf,
                                               const unsigned short* __restrict__ Bq,
                                               const unsigned short* __restrict__ Bk,
                                               const float* __restrict__ bq,
                                               const float* __restrict__ bk,
                                               unsigned short* __restrict__ qbf,
                                               unsigned short* __restrict__ kvbf, int M) {
    int wave = threadIdx.x >> 6, lane = threadIdx.x & 63;
    int base = blockIdx.x * 64 + wave * 16;
    int m = lane & 15, kg = lane >> 4;
    int arow = base + m; if (arow >= M) arow = M - 1;
    const unsigned short* Aptr = Abf + (size_t)arow * 128 + kg * 8;
    f32x4 aq[8], ak[8];
#pragma unroll
    for (int nt = 0; nt < 8; ++nt) { aq[nt] = (f32x4)(0.f); ak[nt] = (f32x4)(0.f); }
#pragma unroll
    for (int kc = 0; kc < 4; ++kc) {
        bf16x8 a = *(const bf16x8*)(Aptr + kc * 32);
        size_t boff = (size_t)kc * 4096 + (size_t)lane * 8;
#pragma unroll
        for (int nt = 0; nt < 8; ++nt) {
            bf16x8 b0 = *(const bf16x8*)(Bq + boff + nt * 512);
            aq[nt] = __builtin_amdgcn_mfma_f32_16x16x32_bf16(a, b0, aq[nt], 0, 0, 0);
            bf16x8 b1 = *(const bf16x8*)(Bk + boff + nt * 512);
            ak[nt] = __builtin_amdgcn_mfma_f32_16x16x32_bf16(a, b1, ak[nt], 0, 0, 0);
        }
    }
    int col0 = lane & 15;
    int r0 = base + (lane >> 4) * 4;
    float4 bql = *(const float4*)&bq[col0 * 8], bqh = *(const float4*)&bq[col0 * 8 + 4];
    float4 bkl = *(const float4*)&bk[col0 * 8], bkh = *(const float4*)&bk[col0 * 8 + 4];
#pragma unroll
    for (int r = 0; r < 4; ++r) {
        int ro = r0 + r;
        if (ro < M) {
            size_t qo = (size_t)ro * 128 + col0 * 8;
            size_t kvo = (size_t)ro * 256 + col0 * 8;
            *(uint4*)&qbf[qo] = make_uint4(
                f2bf2(aq[0][r] + bql.x, aq[1][r] + bql.y), f2bf2(aq[2][r] + bql.z, aq[3][r] + bql.w),
                f2bf2(aq[4][r] + bqh.x, aq[5][r] + bqh.y), f2bf2(aq[6][r] + bqh.z, aq[7][r] + bqh.w));
            *(uint4*)&kvbf[kvo] = make_uint4(
                f2bf2(ak[0][r] + bkl.x, ak[1][r] + bkl.y), f2bf2(ak[2][r] + bkl.z, ak[3][r] + bkl.w),
                f2bf2(ak[4][r] + bkh.x, ak[5][r] + bkh.y), f2bf2(ak[6][r] + bkh.z, ak[7][r] + bkh.w));
        }
    }
}

// ---------- 2-matrix fused GEMM: v -> kvbf[128..256), skip -> xrbf (both bf16) ----------
// Block 0 also zeroes the BN-stat replica buffers (stream order precedes attn's atomics).
__global__ __launch_bounds__(256) void gemm_vs(const unsigned short* __restrict__ Abf,
                                               const unsigned short* __restrict__ Bv,
                                               const unsigned short* __restrict__ Bs,
                                               const float* __restrict__ bv,
                                               const float* __restrict__ bs,
                                               unsigned short* __restrict__ kvbf,
                                               unsigned short* __restrict__ xrbf,
                                               float* __restrict__ bstatZ, int M) {
    if (blockIdx.x == 0) {
        ((float2*)bstatZ)[threadIdx.x] = make_float2(0.f, 0.f);
        ((float2*)bstatZ)[256 + threadIdx.x] = make_float2(0.f, 0.f);
        ((float2*)bstatZ)[512 + threadIdx.x] = make_float2(0.f, 0.f);
        ((float2*)bstatZ)[768 + threadIdx.x] = make_float2(0.f, 0.f);
    }
    int wave = threadIdx.x >> 6, lane = threadIdx.x & 63;
    int base = blockIdx.x * 64 + wave * 16;
    int m = lane & 15, kg = lane >> 4;
    int arow = base + m; if (arow >= M) arow = M - 1;
    const unsigned short* Aptr = Abf + (size_t)arow * 128 + kg * 8;
    f32x4 av[8], as_[8];
#pragma unroll
    for (int nt = 0; nt < 8; ++nt) { av[nt] = (f32x4)(0.f); as_[nt] = (f32x4)(0.f); }
#pragma unroll
    for (int kc = 0; kc < 4; ++kc) {
        bf16x8 a = *(const bf16x8*)(Aptr + kc * 32);
        size_t boff = (size_t)kc * 4096 + (size_t)lane * 8;
#pragma unroll
        for (int nt = 0; nt < 8; ++nt) {
            bf16x8 b2 = *(const bf16x8*)(Bv + boff + nt * 512);
            av[nt] = __builtin_amdgcn_mfma_f32_16x16x32_bf16(a, b2, av[nt], 0, 0, 0);
            bf16x8 b3 = *(const bf16x8*)(Bs + boff + nt * 512);
            as_[nt] = __builtin_amdgcn_mfma_f32_16x16x32_bf16(a, b3, as_[nt], 0, 0, 0);
        }
    }
    int col0 = lane & 15;
    int r0 = base + (lane >> 4) * 4;
    float4 bvl = *(const float4*)&bv[col0 * 8], bvh = *(const float4*)&bv[col0 * 8 + 4];
    float4 bsl = *(const float4*)&bs[col0 * 8], bsh = *(const float4*)&bs[col0 * 8 + 4];
#pragma unroll
    for (int r = 0; r < 4; ++r) {
        int ro = r0 + r;
        if (ro < M) {
            size_t qo = (size_t)ro * 128 + col0 * 8;
            size_t kvo = (size_t)ro * 256 + 128 + col0 * 8;
            *(uint4*)&kvbf[kvo] = make_uint4(
                f2bf2(av[0][r] + bvl.x, av[1][r] + bvl.y), f2bf2(av[2][r] + bvl.z, av[3][r] + bvl.w),
                f2bf2(av[4][r] + bvh.x, av[5][r] + bvh.y), f2bf2(av[6][r] + bvh.z, av[7][r] + bvh.w));
            *(uint4*)&xrbf[qo] = make_uint4(
                f2bf2(as_[0][r] + bsl.x, as_[1][r] + bsl.y), f2bf2(as_[2][r] + bsl.z, as_[3][r] + bsl.w),
                f2bf2(as_[4][r] + bsh.x, as_[5][r] + bsh.y), f2bf2(as_[6][r] + bsh.z, as_[7][r] + bsh.w));
        }
    }
}

// ---------- CSR build ----------
__global__ __launch_bounds__(256) void csr_hist(const int* __restrict__ ei,
                                                int* __restrict__ deg, int E) {
    int e = blockIdx.x * 256 + threadIdx.x;
    if (e < E) atomicAdd(&deg[ei[E + e]], 1);
}

__global__ __launch_bounds__(256) void scan_block_sums(const int* __restrict__ deg,
                                                       int* __restrict__ bsums, int N) {
    __shared__ int sd[256];
    int i = blockIdx.x * 256 + threadIdx.x;
    sd[threadIdx.x] = (i < N) ? deg[i] : 0;
    __syncthreads();
    for (int off = 128; off > 0; off >>= 1) {
        if (threadIdx.x < off) sd[threadIdx.x] += sd[threadIdx.x + off];
        __syncthreads();
    }
    if (threadIdx.x == 0) bsums[blockIdx.x] = sd[0];
}

__global__ __launch_bounds__(256) void scan_bsums(const int* __restrict__ bsums,
                                                  int* __restrict__ boff, int nb) {
    __shared__ int sd[256];
    int tid = threadIdx.x;
    int per = (nb + 255) / 256;
    int start = tid * per;
    int s = 0;
    for (int i = 0; i < per; ++i) {
        int idx = start + i;
        if (idx < nb) s += bsums[idx];
    }
    int my = s;
    sd[tid] = s;
    __syncthreads();
    for (int off = 1; off < 256; off <<= 1) {
        int t = (tid >= off) ? sd[tid - off] : 0;
        __syncthreads();
        sd[tid] += t;
        __syncthreads();
    }
    int run = sd[tid] - my;
    for (int i = 0; i < per; ++i) {
        int idx = start + i;
        if (idx < nb) {
            boff[idx] = run;
            run += bsums[idx];
        }
    }
}

__global__ __launch_bounds__(256) void scan_local(const int* __restrict__ deg,
                                                  const int* __restrict__ boff,
                                                  int* __restrict__ rowptr,
                                                  int* __restrict__ wrptr, int N, int E) {
    __shared__ int sd[256];
    int i = blockIdx.x * 256 + threadIdx.x;
    int v = (i < N) ? deg[i] : 0;
    sd[threadIdx.x] = v;
    __syncthreads();
    for (int off = 1; off < 256; off <<= 1) {
        int t = (threadIdx.x >= off) ? sd[threadIdx.x - off] : 0;
        __syncthreads();
        sd[threadIdx.x] += t;
        __syncthreads();
    }
    if (i < N) {
        int excl = sd[threadIdx.x] - v + boff[blockIdx.x];
        rowptr[i] = excl;
        wrptr[i] = excl;
        if (i == N - 1) rowptr[N] = E;
    }
}

__global__ __launch_bounds__(256) void csr_fill(const int* __restrict__ ei,
                                                const float* __restrict__ ea,
                                                int* __restrict__ wrptr,
                                                int2* __restrict__ csr_sw, int E) {
    int e = blockIdx.x * 256 + threadIdx.x;
    if (e >= E) return;
    int tgt = ei[E + e];
    int pos = atomicAdd(&wrptr[tgt], 1);
    csr_sw[pos] = make_int2(ei[e], __float_as_int(ea[e]));
}

// ---------- attention gather v7: 16 lanes/node, sw 2-ahead / kv 1-ahead, bf16 xr ----------
__global__ __launch_bounds__(256) void attn_gather(const unsigned short* __restrict__ qbf,
                                                   const unsigned short* __restrict__ kvbf,
                                                   const unsigned short* __restrict__ xrbf,
                                                   const int* __restrict__ rowptr,
                                                   const int2* __restrict__ csr_sw,
                                                   const float* __restrict__ Wel,
                                                   const float* __restrict__ Wb,
                                                   float* __restrict__ out,
                                                   float* __restrict__ bsumR,
                                                   float* __restrict__ bsumsqR, int N) {
    __shared__ float sdS[4][128];
    __shared__ float sdQ[4][128];
    int tid = threadIdx.x;
    int n = blockIdx.x * 16 + (tid >> 4);
    int sl = tid & 15;
    int wave = tid >> 6, lane = tid & 63;
    bool live = (n < N);
    int nn = live ? n : (N - 1);

    uint4 qu = ((const uint4*)(qbf + (size_t)nn * 128))[sl];
    float qf[8];
    bfu2(qu.x, qf[0], qf[1]); bfu2(qu.y, qf[2], qf[3]);
    bfu2(qu.z, qf[4], qf[5]); bfu2(qu.w, qf[6], qf[7]);
    float wef[8];
    {
        float4 w0 = ((const float4*)Wel)[sl * 2];
        float4 w1 = ((const float4*)Wel)[sl * 2 + 1];
        wef[0] = w0.x; wef[1] = w0.y; wef[2] = w0.z; wef[3] = w0.w;
        wef[4] = w1.x; wef[5] = w1.y; wef[6] = w1.z; wef[7] = w1.w;
    }
    float qwe = 0.f;
#pragma unroll
    for (int c = 0; c < 8; ++c) qwe += qf[c] * wef[c];
    qwe += __shfl_xor(qwe, 1);
    qwe += __shfl_xor(qwe, 2);

    float l = 0.f;
    float acc[8];
#pragma unroll
    for (int c = 0; c < 8; ++c) acc[c] = 0.f;

    int beg = live ? rowptr[nn] : 0;
    int end = live ? rowptr[nn + 1] : 0;

    if (beg < end) {
        int2 sw0 = csr_sw[beg];
        int j1 = (beg + 1 < end) ? beg + 1 : beg;
        int2 sw1 = csr_sw[j1];
        const uint4* r0 = (const uint4*)(kvbf + (size_t)sw0.x * 256);
        uint4 ku = r0[sl], vu = r0[16 + sl];

        for (int i = beg; i < end; ++i) {
            const uint4* r1 = (const uint4*)(kvbf + (size_t)sw1.x * 256);
            uint4 kun = r1[sl], vun = r1[16 + sl];
            int j2 = (i + 2 < end) ? i + 2 : beg;
            int2 sw2 = csr_sw[j2];

            float w = __int_as_float(sw0.y);
            float kf[8];
            bfu2(ku.x, kf[0], kf[1]); bfu2(ku.y, kf[2], kf[3]);
            bfu2(ku.z, kf[4], kf[5]); bfu2(ku.w, kf[6], kf[7]);
            float d = 0.f;
#pragma unroll
            for (int c = 0; c < 8; ++c) d += qf[c] * kf[c];
            d += __shfl_xor(d, 1); d += __shfl_xor(d, 2);
            float p = __expf((d + w * qwe) * 0.17677669529663687f);
            l += p;
            float vf[8];
            bfu2(vu.x, vf[0], vf[1]); bfu2(vu.y, vf[2], vf[3]);
            bfu2(vu.z, vf[4], vf[5]); bfu2(vu.w, vf[6], vf[7]);
#pragma unroll
            for (int c = 0; c < 8; ++c)
                acc[c] += p * (vf[c] + w * wef[c]);

            sw0 = sw1; sw1 = sw2;
            ku = kun; vu = vun;
        }
    }

    float inv = (l > 0.f) ? 1.f / l : 0.f;
    float ox[8];
#pragma unroll
    for (int c = 0; c < 8; ++c) ox[c] = acc[c] * inv;

    uint4 xu = ((const uint4*)(xrbf + (size_t)nn * 128))[sl];
    float xv[8];
    bfu2(xu.x, xv[0], xv[1]); bfu2(xu.y, xv[2], xv[3]);
    bfu2(xu.z, xv[4], xv[5]); bfu2(xu.w, xv[6], xv[7]);
    float4 b0 = ((const float4*)Wb)[sl * 2];
    float4 b1 = ((const float4*)Wb)[sl * 2 + 1];
    float4 c0 = ((const float4*)(Wb + 128))[sl * 2];
    float4 c1 = ((const float4*)(Wb + 128))[sl * 2 + 1];
    float4 d0 = ((const float4*)(Wb + 256))[sl * 2];
    float4 d1 = ((const float4*)(Wb + 256))[sl * 2 + 1];
    float wb0[8] = {b0.x, b0.y, b0.z, b0.w, b1.x, b1.y, b1.z, b1.w};
    float wb1[8] = {c0.x, c0.y, c0.z, c0.w, c1.x, c1.y, c1.z, c1.w};
    float wb2[8] = {d0.x, d0.y, d0.z, d0.w, d1.x, d1.y, d1.z, d1.w};
    float part = 0.f;
#pragma unroll
    for (int c = 0; c < 8; ++c)
        part += ox[c] * wb0[c] + xv[c] * wb1[c] + (ox[c] - xv[c]) * wb2[c];
    part += __shfl_xor(part, 1); part += __shfl_xor(part, 2);
    part += __shfl_xor(part, 4); part += __shfl_xor(part, 8);
    float beta = 1.f / (1.f + __expf(-part));

    float r[8];
#pragma unroll
    for (int c = 0; c < 8; ++c)
        r[c] = beta * xv[c] + (1.f - beta) * ox[c];

    if (live) {
        ((float4*)(out + (size_t)n * 128))[sl * 2] =
            make_float4(r[0], r[1], r[2], r[3]);
        ((float4*)(out + (size_t)n * 128))[sl * 2 + 1] =
            make_float4(r[4], r[5], r[6], r[7]);
    }

    // ---- fused BN stats ----
    float s8[8], q8[8];
#pragma unroll
    for (int c = 0; c < 8; ++c) {
        s8[c] = live ? r[c] : 0.f;
        q8[c] = live ? r[c] * r[c] : 0.f;
    }
#pragma unroll
    for (int c = 0; c < 8; ++c) {
        s8[c] += __shfl_xor(s8[c], 16); s8[c] += __shfl_xor(s8[c], 32);
        q8[c] += __shfl_xor(q8[c], 16); q8[c] += __shfl_xor(q8[c], 32);
    }
    if ((lane >> 4) == 0) {
#pragma unroll
        for (int c = 0; c < 8; ++c) {
            sdS[wave][sl * 8 + c] = s8[c];
            sdQ[wave][sl * 8 + c] = q8[c];
        }
    }
    __syncthreads();
    if (tid < 128) {
        float s = sdS[0][tid] + sdS[1][tid] + sdS[2][tid] + sdS[3][tid];
        float q = sdQ[0][tid] + sdQ[1][tid] + sdQ[2][tid] + sdQ[3][tid];
        int rep = blockIdx.x & 7;
        atomicAdd(&bsumR[rep * 128 + tid], s);
        atomicAdd(&bsumsqR[rep * 128 + tid], q);
    }
}

// ---------- BN apply + ReLU + residual (+ optional bf16 side-write), 8-replica stats ----------
__global__ __launch_bounds__(256) void bn_apply(const float* __restrict__ o,
                                                const float* __restrict__ hres,
                                                float* __restrict__ hout,
                                                unsigned short* __restrict__ hout_bf,
                                                const float* __restrict__ bsumR,
                                                const float* __restrict__ bsumsqR,
                                                const float* __restrict__ gamma,
                                                const float* __restrict__ bbeta,
                                                int N, float invN) {
    int i = blockIdx.x * 256 + threadIdx.x;
    if (i >= N * 32) return;
    int c4 = i & 31;
    float4 s = make_float4(0.f, 0.f, 0.f, 0.f), ss = s;
#pragma unroll
    for (int rep = 0; rep < 8; ++rep) {
        float4 sv = ((const float4*)bsumR)[rep * 32 + c4];
        float4 qv = ((const float4*)bsumsqR)[rep * 32 + c4];
        s.x += sv.x; s.y += sv.y; s.z += sv.z; s.w += sv.w;
        ss.x += qv.x; ss.y += qv.y; ss.z += qv.z; ss.w += qv.w;
    }
    float4 g = ((const float4*)gamma)[c4];
    float4 b = ((const float4*)bbeta)[c4];
    float4 ov = ((const float4*)o)[i];
    float4 hr = ((const float4*)hres)[i];
    float4 r;
    { float mu = s.x * invN, var = ss.x * invN - mu * mu;
      r.x = fmaxf((ov.x - mu) * (g.x * rsqrtf(var + EPS)) + b.x, 0.f) + hr.x; }
    { float mu = s.y * invN, var = ss.y * invN - mu * mu;
      r.y = fmaxf((ov.y - mu) * (g.y * rsqrtf(var + EPS)) + b.y, 0.f) + hr.y; }
    { float mu = s.z * invN, var = ss.z * invN - mu * mu;
      r.z = fmaxf((ov.z - mu) * (g.z * rsqrtf(var + EPS)) + b.z, 0.f) + hr.z; }
    { float mu = s.w * invN, var = ss.w * invN - mu * mu;
      r.w = fmaxf((ov.w - mu) * (g.w * rsqrtf(var + EPS)) + b.w, 0.f) + hr.w; }
    ((float4*)hout)[i] = r;
    if (hout_bf) {
        ushort4 ob = make_ushort4(f2bf(r.x), f2bf(r.y), f2bf(r.z), f2bf(r.w));
        ((ushort4*)hout_bf)[i] = ob;
    }
}

extern "C" void kernel_launch(void* const* d_in, const int* in_sizes, int n_in,
                              void* d_out, int out_size, void* d_ws, size_t ws_size,
                              hipStream_t stream) {
    const float* x     = (const float*)d_in[0];
    const int*   ei    = (const int*)d_in[1];
    const float* ea    = (const float*)d_in[2];
    const float* W_in  = (const float*)d_in[3];
    const float* b_in  = (const float*)d_in[4];
    const float* Wq    = (const float*)d_in[5];
    const float* bq    = (const float*)d_in[6];
    const float* Wk    = (const float*)d_in[7];
    const float* bk    = (const float*)d_in[8];
    const float* Wv    = (const float*)d_in[9];
    const float* bv    = (const float*)d_in[10];
    const float* We    = (const float*)d_in[11];
    const float* Wskip = (const float*)d_in[12];
    const float* bskip = (const float*)d_in[13];
    const float* Wbeta = (const float*)d_in[14];
    const float* bn_g  = (const float*)d_in[15];
    const float* bn_b  = (const float*)d_in[16];

    const int N = in_sizes[0] / 128;
    const int E = in_sizes[1] / 2;

    float* ws = (float*)d_ws;
    unsigned short* Bpack = (unsigned short*)ws;           // 9*16384 bf16 = 73728 floats
    size_t off = 73728;
    unsigned short* xbf  = (unsigned short*)(ws + off);               off += (size_t)N * 64;
    unsigned short* hbf  = (unsigned short*)(ws + off);               off += (size_t)N * 64;
    unsigned short* qbf  = (unsigned short*)(ws + off);               off += (size_t)N * 64;
    unsigned short* kvbf = (unsigned short*)(ws + off);               off += (size_t)N * 128;
    unsigned short* xrbf = (unsigned short*)(ws + off);               off += (size_t)N * 64;
    float* h    = ws + off;  off += (size_t)N * 128;
    float* attn = ws + off;  off += (size_t)N * 128;
    float* bsumR   = ws + off;  off += 1024;               // 8 replicas x 128
    float* bsumsqR = ws + off;  off += 1024;               // contiguous after bsumR
    int2* csr_sw = (int2*)(ws + off);  off += (size_t)E * 2;
    int* deg     = (int*)(ws + off);
    int* rowptr  = deg + N;
    int* wrptr   = rowptr + (N + 1);
    int* bsums   = wrptr + N;
    int* boff    = bsums + ((N + 255) / 256 + 1);

    dim3 blk(256);
    int gGemm   = (N + 63) / 64;
    int gNode16 = (N + 15) / 16;
    int gEdge   = (E + 255) / 256;
    int gApply  = (N * 32 + 255) / 256;
    int nbScan  = (N + 255) / 256;

    // ---- fused prep: x->bf16 | weight pack | deg zero ----
    int nConv = gApply;                 // (N*32+255)/256 blocks for x conversion
    int nPack = (9 * 16384 + 255) / 256;
    prep<<<nConv + nPack + nbScan, blk, 0, stream>>>(
        x, xbf, N * 32,
        W_in, Wq, Wk, Wv, Wskip, Wq + 16384, Wk + 16384, Wv + 16384, Wskip + 16384,
        Bpack, deg, N, nConv, nPack);

    // ---- CSR build ----
    csr_hist<<<gEdge, blk, 0, stream>>>(ei, deg, E);
    scan_block_sums<<<nbScan, blk, 0, stream>>>(deg, bsums, N);
    scan_bsums<<<1, blk, 0, stream>>>(bsums, boff, nbScan);
    scan_local<<<nbScan, blk, 0, stream>>>(deg, boff, rowptr, wrptr, N, E);
    csr_fill<<<gEdge, blk, 0, stream>>>(ei, ea, wrptr, csr_sw, E);

    // ---- input projection (writes h fp32 + hbf bf16) ----
    gemm_mfma<1, 1><<<gGemm, blk, 0, stream>>>(xbf, Bpack + 0 * 16384, b_in, h, hbf, N);

    for (int l = 0; l < 2; ++l) {
        const unsigned short* Bq = Bpack + (size_t)(1 + l * 4 + 0) * 16384;
        const unsigned short* Bk = Bpack + (size_t)(1 + l * 4 + 1) * 16384;
        const unsigned short* Bv = Bpack + (size_t)(1 + l * 4 + 2) * 16384;
        const unsigned short* Bs = Bpack + (size_t)(1 + l * 4 + 3) * 16384;
        gemm_qk<<<gGemm, blk, 0, stream>>>(hbf, Bq, Bk, bq + l * 128, bk + l * 128,
                                           qbf, kvbf, N);
        gemm_vs<<<gGemm, blk, 0, stream>>>(hbf, Bv, Bs, bv + l * 128, bskip + l * 128,
                                           kvbf, xrbf, bsumR, N);
        attn_gather<<<gNode16, blk, 0, stream>>>(qbf, kvbf, xrbf, rowptr, csr_sw,
                                                 We + l * 128, Wbeta + l * 384, attn,
                                                 bsumR, bsumsqR, N);
        bn_apply<<<gApply, blk, 0, stream>>>(attn, h, (l == 1) ? (float*)d_out : h,
                                             (l == 0) ? hbf : (unsigned short*)0,
                                             bsumR, bsumsqR, bn_g + l * 128, bn_b + l * 128,
                                             N, 1.0f / (float)N);
    }
}